// Round 26
// baseline (211.733 us; speedup 1.0000x reference)
//
#include <hip/hip_runtime.h>

#define NB 8192
#define NBH 4096   // batch elements per slot; lane handles b and b+NBH
#define NT 365
#define NF 5
#define NH 10
#define NG 40
#define GPW 6      // 10-lane groups per wave (lanes 60..63 dead)

// DUAL-ELEMENT r13/r19: one lane owns hidden unit u of TWO independent
// batch elements (b < 4096 and b+4096). The second element's issue stream
// fills the first's dependency stalls (dot dep + exp/rcp chains + bperm
// round-trip ~500-650cyc/step that r7-r25 proved invariant to everything
// else at ~1 wave/SIMD). Weights/addresses/loop overhead are SHARED -- per
// batch-element issue drops ~40% vs r25. 683 waves -> 171 blocks: every CU
// <= 1 block (kills r25's 2-waves-on-86-CUs imbalance).
// Per-element math byte-identical to r13 (absmax 0.0078125).
// x staged through per-wave LDS double-buffers (r19 path) to keep VGPR
// demand compatible with 2x state.
__global__ __launch_bounds__(256, 1)
void lstm_dual(const float* __restrict__ x,
               const float* __restrict__ w_ih,
               const float* __restrict__ w_hh,
               const float* __restrict__ bias,
               const float* __restrict__ fc_w,
               const float* __restrict__ fc_b,
               float* __restrict__ out)
{
    __shared__ float xlds[4 * 960];  // [wave][elem][buf][6 groups][40]

    const int tid  = threadIdx.x;
    const int lane = tid & 63;
    const int wv   = tid >> 6;
    const int wid  = (blockIdx.x * 256 + tid) >> 6;  // global wave id
    const int g    = lane / NH;          // group (0..5; 6 => dead)
    const int u    = lane % NH;          // owned hidden unit
    const long b0  = (long)wid * GPW + g;
    const bool alive = (g < GPW) && (b0 < NBH);
    const long b  = alive ? b0 : 0;      // clamped
    const long b2 = b + NBH;             // always valid (< 8192)

    float* h_out = out + NB;
    float* c_out = h_out + (size_t)NB * NT * NH;

    // ---- per-lane weights (r13 verbatim; shared by both elements) ----
    float wih[NF][4], whh[NH][4], bq[4];
    #pragma unroll
    for (int q = 0; q < 4; ++q) {
        const float gs = (q == 3) ? 2.0f : 1.0f;
        const int col = q * NH + u;
        #pragma unroll
        for (int f = 0; f < NF; ++f) wih[f][q] = w_ih[f * NG + col] * gs;
        #pragma unroll
        for (int j = 0; j < NH; ++j) whh[j][q] = w_hh[j * NG + col] * gs;
        bq[q] = bias[col] * gs;
    }

    int aj[NH];
    #pragma unroll
    for (int j = 0; j < NH; ++j) aj[j] = (g * NH + j) * 4;

    float h1[NH], h2[NH];
    #pragma unroll
    for (int j = 0; j < NH; ++j) { h1[j] = 0.f; h2[j] = 0.f; }
    float cv1 = 0.f, cv2 = 0.f;

    const float* xp1 = x + (size_t)b  * NT * NF;
    const float* xp2 = x + (size_t)b2 * NT * NF;
    float* hp1 = h_out + (size_t)b  * NT * NH + u;
    float* cp1 = c_out + (size_t)b  * NT * NH + u;
    float* hp2 = h_out + (size_t)b2 * NT * NH + u;
    float* cp2 = c_out + (size_t)b2 * NT * NH + u;

    float* L   = &xlds[wv * 960];
    float* w10 = L +   0 + g * 40;   // elem1 buf0 (this lane's group)
    float* w11 = L + 240 + g * 40;   // elem1 buf1
    float* w20 = L + 480 + g * 40;   // elem2 buf0
    float* w21 = L + 720 + g * 40;   // elem2 buf1

    float4 G1, G2; float Gx1 = 0.f, Gx2 = 0.f;

// stage one 8-step x chunk for both elements (lane u loads quarter u)
#define GLOAD(t0) { \
    G1 = *reinterpret_cast<const float4*>(xp1 + (size_t)(t0) * NF + u * 4); \
    G2 = *reinterpret_cast<const float4*>(xp2 + (size_t)(t0) * NF + u * 4); }
#define WRITE(d1, d2) { if (g < GPW) { \
    *reinterpret_cast<float4*>((d1) + u * 4) = G1; \
    *reinterpret_cast<float4*>((d2) + u * 4) = G2; } }
// tail chunk: 25 floats (t=360..364)
#define GLOADT { \
    if (u < 6) { \
        G1 = *reinterpret_cast<const float4*>(xp1 + 1800 + u * 4); \
        G2 = *reinterpret_cast<const float4*>(xp2 + 1800 + u * 4); \
    } else if (u == 6) { Gx1 = xp1[1824]; Gx2 = xp2[1824]; } }
#define WRITET(d1, d2) { if (g < GPW) { \
    if (u < 6) { \
        *reinterpret_cast<float4*>((d1) + u * 4) = G1; \
        *reinterpret_cast<float4*>((d2) + u * 4) = G2; \
    } else if (u == 6) { (d1)[24] = Gx1; (d2)[24] = Gx2; } } }

// one dual step; s literal. Two independent chains interleaved at source.
#define STEP2(X1, X2, s) { \
    float p0 = bq[0], p1 = bq[1], p2 = bq[2], p3 = bq[3]; \
    float q0 = bq[0], q1 = bq[1], q2 = bq[2], q3 = bq[3]; \
    _Pragma("unroll") \
    for (int f = 0; f < NF; ++f) { \
        const float xa = (X1)[(s) * NF + f]; \
        const float xc = (X2)[(s) * NF + f]; \
        p0 = fmaf(xa, wih[f][0], p0); p1 = fmaf(xa, wih[f][1], p1); \
        p2 = fmaf(xa, wih[f][2], p2); p3 = fmaf(xa, wih[f][3], p3); \
        q0 = fmaf(xc, wih[f][0], q0); q1 = fmaf(xc, wih[f][1], q1); \
        q2 = fmaf(xc, wih[f][2], q2); q3 = fmaf(xc, wih[f][3], q3); } \
    _Pragma("unroll") \
    for (int j = 0; j < NH; ++j) { \
        const float ha = h1[j]; const float hc = h2[j]; \
        p0 = fmaf(ha, whh[j][0], p0); p1 = fmaf(ha, whh[j][1], p1); \
        p2 = fmaf(ha, whh[j][2], p2); p3 = fmaf(ha, whh[j][3], p3); \
        q0 = fmaf(hc, whh[j][0], q0); q1 = fmaf(hc, whh[j][1], q1); \
        q2 = fmaf(hc, whh[j][2], q2); q3 = fmaf(hc, whh[j][3], q3); } \
    const float sf1 = __builtin_amdgcn_rcpf(1.0f + __expf(-p0)); \
    const float si1 = __builtin_amdgcn_rcpf(1.0f + __expf(-p1)); \
    const float so1 = __builtin_amdgcn_rcpf(1.0f + __expf(-p2)); \
    const float tg1 = fmaf(2.0f, __builtin_amdgcn_rcpf(1.0f + __expf(-p3)), -1.0f); \
    const float sf2 = __builtin_amdgcn_rcpf(1.0f + __expf(-q0)); \
    const float si2 = __builtin_amdgcn_rcpf(1.0f + __expf(-q1)); \
    const float so2 = __builtin_amdgcn_rcpf(1.0f + __expf(-q2)); \
    const float tg2 = fmaf(2.0f, __builtin_amdgcn_rcpf(1.0f + __expf(-q3)), -1.0f); \
    cv1 = fmaf(sf1, cv1, si1 * tg1); \
    cv2 = fmaf(sf2, cv2, si2 * tg2); \
    const float th1 = fmaf(2.0f, __builtin_amdgcn_rcpf(1.0f + __expf(-2.0f * cv1)), -1.0f); \
    const float th2 = fmaf(2.0f, __builtin_amdgcn_rcpf(1.0f + __expf(-2.0f * cv2)), -1.0f); \
    const float hv1 = so1 * th1; \
    const float hv2 = so2 * th2; \
    _Pragma("unroll") \
    for (int j = 0; j < NH; ++j) { \
        h1[j] = __int_as_float(__builtin_amdgcn_ds_bpermute(aj[j], __float_as_int(hv1))); \
        h2[j] = __int_as_float(__builtin_amdgcn_ds_bpermute(aj[j], __float_as_int(hv2))); } \
    if (alive) { \
        hp1[(s) * NH] = hv1; cp1[(s) * NH] = cv1; \
        hp2[(s) * NH] = hv2; cp2[(s) * NH] = cv2; } }

#define RUN8(X1, X2) { STEP2(X1, X2, 0) STEP2(X1, X2, 1) STEP2(X1, X2, 2) \
    STEP2(X1, X2, 3) STEP2(X1, X2, 4) STEP2(X1, X2, 5) STEP2(X1, X2, 6) \
    STEP2(X1, X2, 7) \
    hp1 += 8 * NH; cp1 += 8 * NH; hp2 += 8 * NH; cp2 += 8 * NH; }

    // prologue: chunk 0 -> buf0 (both elements)
    GLOAD(0) WRITE(w10, w20)
    // 44 full chunks in 22 ping-pong pairs (t = 0..351)
    for (int cc = 0; cc < 22; ++cc) {
        GLOAD(16 * cc + 8)          // next chunk issued before 8 steps
        RUN8(w10, w20)              // run current (buf0)
        WRITE(w11, w21)
        GLOAD(16 * cc + 16)         // cc=21 -> t0=352, in-bounds
        RUN8(w11, w21)              // run buf1
        WRITE(w10, w20)
    }
    // buf0 = chunk 44 (t=352..359); stage tail, run, then 5 tail steps
    GLOADT
    RUN8(w10, w20)
    WRITET(w11, w21)
    { STEP2(w11, w21, 0) STEP2(w11, w21, 1) STEP2(w11, w21, 2)
      STEP2(w11, w21, 3) STEP2(w11, w21, 4) }   // t = 360..364

    // ---- fc head: lane u==0 has full h for both elements ----
    if (alive && u == 0) {
        float a1 = fc_b[0], a2 = fc_b[0];
        #pragma unroll
        for (int j = 0; j < NH; ++j) {
            a1 = fmaf(h1[j], fc_w[j], a1);
            a2 = fmaf(h2[j], fc_w[j], a2);
        }
        out[b] = a1; out[b2] = a2;
    }
}

extern "C" void kernel_launch(void* const* d_in, const int* in_sizes, int n_in,
                              void* d_out, int out_size, void* d_ws, size_t ws_size,
                              hipStream_t stream) {
    const float* x    = (const float*)d_in[0];
    const float* wih  = (const float*)d_in[1];
    const float* whh  = (const float*)d_in[2];
    const float* bias = (const float*)d_in[3];
    const float* fcw  = (const float*)d_in[4];
    const float* fcb  = (const float*)d_in[5];
    float* out = (float*)d_out;

    const int nwave  = (NBH + GPW - 1) / GPW;         // 683 waves
    const int blocks = (nwave * 64 + 255) / 256;      // 171 blocks
    lstm_dual<<<blocks, 256, 0, stream>>>(x, wih, whh, bias, fcw, fcb, out);
}

// Round 27
// 157.442 us; speedup vs baseline: 1.3448x; 1.3448x over previous
//
#include <hip/hip_runtime.h>

#define NB 8192
#define NT 365
#define NF 5
#define NH 10
#define NG 40
#define GPW 4    // 4 batch elements per wave, 16-lane groups (u<10 active)

// r13 math verbatim (best-verified: absmax 0.0078125). One lane owns one
// hidden unit u of one batch element; 10 ds_bpermute/step broadcast h;
// g-gate weights pre-scaled x2; x prefetched in 8-step register chunks.
//
// NEW vs r25: occupancy reshape for UNIFORM latency hiding. 16-lane groups
// (g=lane>>4, u=lane&15, alive=u<10) x 4 groups = 4 elements/wave ->
// 2048 waves = 256 blocks x 512 threads = exactly 1 block/CU, 8 waves/CU,
// 2 waves/SIMD EVERYWHERE. r25's 342 blocks left 170 CUs at 1 wave/SIMD
// (zero hiding, ~60% effective packing); uniform 2/SIMD trades 1.5x issue
// inflation (24 dead lanes) for ~85% packing. 8192=2048*4 exactly: all b
// valid, no bounds checks; bpermute addr = (lane&48)+j.
__global__ __launch_bounds__(512, 2)
void lstm_u2(const float* __restrict__ x,
             const float* __restrict__ w_ih,
             const float* __restrict__ w_hh,
             const float* __restrict__ bias,
             const float* __restrict__ fc_w,
             const float* __restrict__ fc_b,
             float* __restrict__ out)
{
    const int tid  = threadIdx.x;
    const int lane = tid & 63;
    const int wid  = (blockIdx.x * 512 + tid) >> 6;  // global wave id
    const int g    = lane >> 4;          // group 0..3
    const int u    = lane & 15;          // unit slot; alive if u<10
    const bool alive = (u < NH);
    const int  uc   = alive ? u : 0;     // clamped for weight/x addressing
    const long b    = (long)wid * GPW + g;   // always < 8192

    float* h_out = out + NB;
    float* c_out = h_out + (size_t)NB * NT * NH;

    // ---- per-lane weights (r13 verbatim, col via uc) ----
    float wih[NF][4], whh[NH][4], bq[4];
    #pragma unroll
    for (int q = 0; q < 4; ++q) {
        const float gs = (q == 3) ? 2.0f : 1.0f;
        const int col = q * NH + uc;
        #pragma unroll
        for (int f = 0; f < NF; ++f) wih[f][q] = w_ih[f * NG + col] * gs;
        #pragma unroll
        for (int j = 0; j < NH; ++j) whh[j][q] = w_hh[j * NG + col] * gs;
        bq[q] = bias[col] * gs;
    }

    // bpermute byte-addresses: lane (g*16+j) holds unit j of this group
    int aj[NH];
    #pragma unroll
    for (int j = 0; j < NH; ++j) aj[j] = ((lane & 48) + j) * 4;

    float hAll[NH];
    #pragma unroll
    for (int j = 0; j < NH; ++j) hAll[j] = 0.f;
    float c = 0.f;

    const float* xp = x + (size_t)b * NT * NF;   // 16B-aligned (b*29200B)
    float* hcp = h_out + (size_t)b * NT * NH + uc;
    float* ccp = c_out + (size_t)b * NT * NH + uc;

    float A[40], B[40];   // x double-buffer: 8 steps x 5 features

#define LD8(dst, t0) { \
    const float4* p4 = reinterpret_cast<const float4*>(xp + (size_t)(t0) * NF); \
    _Pragma("unroll") \
    for (int i = 0; i < 10; ++i) { \
        float4 v = p4[i]; \
        dst[i*4+0] = v.x; dst[i*4+1] = v.y; dst[i*4+2] = v.z; dst[i*4+3] = v.w; } }

#define LDT(dst) { \
    const float4* p4 = reinterpret_cast<const float4*>(xp + (size_t)360 * NF); \
    _Pragma("unroll") \
    for (int i = 0; i < 6; ++i) { \
        float4 v = p4[i]; \
        dst[i*4+0] = v.x; dst[i*4+1] = v.y; dst[i*4+2] = v.z; dst[i*4+3] = v.w; } \
    dst[24] = xp[360 * NF + 24]; }

#define STEP(buf, s) { \
    float r0 = bq[0], r1 = bq[1], r2 = bq[2], r3 = bq[3]; \
    _Pragma("unroll") \
    for (int f = 0; f < NF; ++f) { \
        const float xv = buf[(s) * NF + f]; \
        r0 = fmaf(xv, wih[f][0], r0); r1 = fmaf(xv, wih[f][1], r1); \
        r2 = fmaf(xv, wih[f][2], r2); r3 = fmaf(xv, wih[f][3], r3); } \
    _Pragma("unroll") \
    for (int j = 0; j < NH; ++j) { \
        const float hv = hAll[j]; \
        r0 = fmaf(hv, whh[j][0], r0); r1 = fmaf(hv, whh[j][1], r1); \
        r2 = fmaf(hv, whh[j][2], r2); r3 = fmaf(hv, whh[j][3], r3); } \
    const float sf = __builtin_amdgcn_rcpf(1.0f + __expf(-r0)); \
    const float si = __builtin_amdgcn_rcpf(1.0f + __expf(-r1)); \
    const float so = __builtin_amdgcn_rcpf(1.0f + __expf(-r2)); \
    const float tg = fmaf(2.0f, __builtin_amdgcn_rcpf(1.0f + __expf(-r3)), -1.0f); \
    c = fmaf(sf, c, si * tg); \
    const float th = fmaf(2.0f, __builtin_amdgcn_rcpf(1.0f + __expf(-2.0f * c)), -1.0f); \
    const float h = so * th; \
    _Pragma("unroll") \
    for (int j = 0; j < NH; ++j) \
        hAll[j] = __int_as_float(__builtin_amdgcn_ds_bpermute(aj[j], __float_as_int(h))); \
    if (alive) { hcp[(s) * NH] = h; ccp[(s) * NH] = c; } }

#define RUN8(buf) { STEP(buf,0) STEP(buf,1) STEP(buf,2) STEP(buf,3) \
                    STEP(buf,4) STEP(buf,5) STEP(buf,6) STEP(buf,7) \
                    hcp += 8 * NH; ccp += 8 * NH; }

    LD8(A, 0)
    for (int cc = 0; cc < 22; ++cc) {            // t = 0..351
        const int t0 = cc * 16;
        LD8(B, t0 + 8)
        RUN8(A)
        LD8(A, t0 + 16)                          // cc=21 -> t=352, in-bounds
        RUN8(B)
    }
    LDT(B)                                       // tail x: t=360..364
    RUN8(A)                                      // t = 352..359
    { STEP(B,0) STEP(B,1) STEP(B,2) STEP(B,3) STEP(B,4) }   // t=360..364

    // ---- fc head: lane u==0 of each group has full h ----
    if (u == 0) {
        float acc = fc_b[0];
        #pragma unroll
        for (int j = 0; j < NH; ++j) acc = fmaf(hAll[j], fc_w[j], acc);
        out[b] = acc;
    }
}

extern "C" void kernel_launch(void* const* d_in, const int* in_sizes, int n_in,
                              void* d_out, int out_size, void* d_ws, size_t ws_size,
                              hipStream_t stream) {
    const float* x    = (const float*)d_in[0];
    const float* wih  = (const float*)d_in[1];
    const float* whh  = (const float*)d_in[2];
    const float* bias = (const float*)d_in[3];
    const float* fcw  = (const float*)d_in[4];
    const float* fcb  = (const float*)d_in[5];
    float* out = (float*)d_out;

    // 2048 waves = 256 blocks x 8 waves: 1 block/CU, 2 waves/SIMD uniform
    lstm_u2<<<256, 512, 0, stream>>>(x, wih, whh, bias, fcw, fcb, out);
}